// Round 6
// baseline (60.444 us; speedup 1.0000x reference)
//
#include <hip/hip_runtime.h>
#include <math.h>

#define N 512
#define D 256
#define NPAIRS 261632.0f  // 512*511

typedef unsigned long long u64;
// bijective LDS index swizzle for the sort arrays (spread bitonic strides
// across bank pairs); must be applied on EVERY q access.
#define SW(x) ((x) ^ (((x) >> 4) & 15))

__constant__ float kRad2Deg = 57.29577951308232f; // 180/pi

// ---------------------------------------------------------------------------
// Kernel 1: per-row prep. Block = one row i (512 blocks, 64 lanes).
// Lanes: ||f[i]||^2 via float4 + wave reduce. Lane 0: pose 6d->rot (det-
// normalized) + tvec; block 0 zeroes the accumulator and completion counter.
// ---------------------------------------------------------------------------
__global__ __launch_bounds__(64) void prep_kernel(
        const float* __restrict__ f,
        const float* __restrict__ labels,
        float* __restrict__ rot,
        float* __restrict__ tvec,
        float* __restrict__ nrm,
        float* __restrict__ acc,
        unsigned* __restrict__ cnt) {
    const int i = blockIdx.x;
    const int l = threadIdx.x;

    const float4 v = ((const float4*)(f + i * D))[l];   // 64 lanes x 4 = 256
    float ss = v.x * v.x + v.y * v.y + v.z * v.z + v.w * v.w;
#pragma unroll
    for (int off = 32; off > 0; off >>= 1) ss += __shfl_down(ss, off, 64);

    if (l == 0) {
        nrm[i] = ss;
        const float* p = labels + i * 9;
        float a1x = p[0], a1y = p[1], a1z = p[2];
        float a2x = p[3], a2y = p[4], a2z = p[5];
        float n1 = sqrtf(a1x * a1x + a1y * a1y + a1z * a1z);
        float b1x = a1x / n1, b1y = a1y / n1, b1z = a1z / n1;
        float dp = b1x * a2x + b1y * a2y + b1z * a2z;
        float cx = a2x - dp * b1x, cy = a2y - dp * b1y, cz = a2z - dp * b1z;
        float n2 = sqrtf(cx * cx + cy * cy + cz * cz);
        float b2x = cx / n2, b2y = cy / n2, b2z = cz / n2;
        float b3x = b1y * b2z - b1z * b2y;
        float b3y = b1z * b2x - b1x * b2z;
        float b3z = b1x * b2y - b1y * b2x;
        float det = b1x * (b2y * b3z - b2z * b3y)
                  - b1y * (b2x * b3z - b2z * b3x)
                  + b1z * (b2x * b3y - b2y * b3x);
        float inv = 1.0f / cbrtf(det);
        float* r = rot + i * 9;
        r[0] = b1x * inv; r[1] = b1y * inv; r[2] = b1z * inv;
        r[3] = b2x * inv; r[4] = b2y * inv; r[5] = b2z * inv;
        r[6] = b3x * inv; r[7] = b3y * inv; r[8] = b3z * inv;
        tvec[i * 3 + 0] = p[6];
        tvec[i * 3 + 1] = p[7];
        tvec[i * 3 + 2] = p[8];
        if (i == 0) { acc[0] = 0.0f; cnt[0] = 0u; }
    }
}

// ---------------------------------------------------------------------------
// Kernel 2: fully fused per-row. Block = row i, 512 threads (8 waves);
// thread t owns column j = t.
//  Phase 1: dot-form distance d2 = nrm[i]+nrm[j]-2*f_i.f_j (f_i in LDS,
//           f_j streamed per-thread, L1-sequential), pose errors, L/E;
//           pack (key<<32)|E_bits directly into the LDS sort arrays.
//  Phase 2: bitonic sort of both criteria CONCURRENTLY (waves 0-3: TD,
//           waves 4-7: SD — wave-uniform split, shared barriers).
//  Phase 3: suffix-sum of E + tie-run-start max-scan (same wave split).
//  Phase 4: per-position log terms; block contribution =
//           Sum(L) - 0.5*Sum(terms) + diag_part; one atomic; the LAST
//           block to finish computes out[0] (atomic counter + fence).
// denominators-by-sort identity (verified R4/R5): the position sum includes
// the diagonal element's term == log(diag denominator), cancelled by
// diag_part = +0.5*(log a + log b) computed directly.
// ---------------------------------------------------------------------------
__global__ __launch_bounds__(512) void fused_row_kernel(
        const float* __restrict__ f,
        const float* __restrict__ rot,
        const float* __restrict__ tvec,
        const float* __restrict__ nrm,
        float* __restrict__ acc,
        unsigned* __restrict__ cnt,
        float* __restrict__ out) {
    __shared__ __attribute__((aligned(16))) float4 lds_fi[D / 4];
    __shared__ u64   qT[512], qS[512];      // packed (key<<32)|E, swizzled
    __shared__ float sT[512], sS[512];      // suffix sums (unpacked E)
    __shared__ int   lT[512], lS[512];      // tie-run-start (lb) max-scan
    __shared__ float redA[8], redB[8], redC[8];
    __shared__ float sh_dT, sh_dS;

    const int t  = threadIdx.x;             // column j = t
    const int i  = blockIdx.x;
    const int tp = t & 255;
    const int lane = t & 63, wid = t >> 6;

    if (t < D / 4) lds_fi[t] = ((const float4*)(f + i * D))[t];
    __syncthreads();

    // ---- dot(f_i, f_t): per-thread stream of row t (L1-sequential) ----
    float dot = 0.0f;
    const float4* __restrict__ fj4 = (const float4*)(f + t * D);
#pragma unroll 8
    for (int kk = 0; kk < D / 4; ++kk) {
        const float4 v = fj4[kk];
        const float4 a = lds_fi[kk];        // uniform -> LDS broadcast
        dot += a.x * v.x; dot += a.y * v.y; dot += a.z * v.z; dot += a.w * v.w;
    }

    // ---- pose errors for (i, t) ----
    float rj[9];
#pragma unroll
    for (int c = 0; c < 9; ++c) rj[c] = rot[t * 9 + c];
    float tr = 0.0f;
#pragma unroll
    for (int c = 0; c < 9; ++c) tr += rot[i * 9 + c] * rj[c];  // uniform i
    float ct = (tr - 1.0f) * 0.5f;
    ct = fminf(1.0f, fmaxf(-1.0f, ct));
    const float theta = acosf(ct) * kRad2Deg;

    const float dx = tvec[i * 3 + 0] - tvec[t * 3 + 0];
    const float dy = tvec[i * 3 + 1] - tvec[t * 3 + 1];
    const float dz = tvec[i * 3 + 2] - tvec[t * 3 + 2];
    const float sd2 = dx * dx + dy * dy + dz * dz;
    const float shift = (sd2 > 0.0f ? sqrtf(sd2) : 0.0f) * 100.0f;

    const float d2 = nrm[i] + nrm[t] - 2.0f * dot;
    float L, Ev;
    if (t == i) { L = 0.0f; Ev = 0.0f; }    // exact reference diagonal
    else {
        const float dist = (d2 > 0.0f ? sqrtf(d2) : 0.0f);
        L  = -dist * 0.5f;                  // TEMPERATURE=2; rowmax==0 (no-op)
        Ev = expf(L);
    }

    // publish diag thresholds; stage packed sort arrays
    if (t == i) { sh_dT = theta; sh_dS = shift; }
    const u64 eb = (u64)__float_as_uint(Ev);
    qT[SW(t)] = ((u64)__float_as_uint(theta) << 32) | eb;
    qS[SW(t)] = ((u64)__float_as_uint(shift) << 32) | eb;
    __syncthreads();

    // ---- direct diag denominators + Sum(L), block-reduced ----
    float dtd = (theta >= sh_dT) ? Ev : 0.0f;
    float dsd = (shift >= sh_dS) ? Ev : 0.0f;
    float lpart = L;
#pragma unroll
    for (int off = 32; off > 0; off >>= 1) {
        dtd   += __shfl_down(dtd, off, 64);
        dsd   += __shfl_down(dsd, off, 64);
        lpart += __shfl_down(lpart, off, 64);
    }
    if (lane == 0) { redA[wid] = dtd; redB[wid] = dsd; redC[wid] = lpart; }

    // ---- bitonic sort ascending; waves 0-3: qT, waves 4-7: qS ----
    for (unsigned k = 2; k <= 512; k <<= 1) {
        for (unsigned jj = k >> 1; jj >= 1; jj >>= 1) {
            __syncthreads();
            const unsigned a = ((tp & ~(jj - 1)) << 1) | (tp & (jj - 1));
            const unsigned b = a | jj;
            const bool up = ((a & k) == 0);
            if (t < 256) {
                u64 va = qT[SW(a)], vb = qT[SW(b)];
                if (up ? (va > vb) : (va < vb)) { qT[SW(a)] = vb; qT[SW(b)] = va; }
            } else {
                u64 va = qS[SW(a)], vb = qS[SW(b)];
                if (up ? (va > vb) : (va < vb)) { qS[SW(a)] = vb; qS[SW(b)] = va; }
            }
        }
    }
    __syncthreads();

    // thread 0 folds the small reductions while others unpack
    float diag_part = 0.0f, lsum = 0.0f;
    if (t == 0) {
        float a = 0.0f, b = 0.0f;
#pragma unroll
        for (int w = 0; w < 8; ++w) { a += redA[w]; b += redB[w]; lsum += redC[w]; }
        diag_part = 0.5f * (logf(a) + logf(b));
    }

    // ---- unpack: suffix-sum seeds + tie-run head flags (wave split) ----
    if (t < 256) {
        const u64 v0 = qT[SW(tp)], v1 = qT[SW(tp + 256)];
        sT[tp]       = __uint_as_float((unsigned)v0);
        sT[tp + 256] = __uint_as_float((unsigned)v1);
        const unsigned h0 = (unsigned)(v0 >> 32), h1 = (unsigned)(v1 >> 32);
        const unsigned hp = (unsigned)(qT[SW(tp + 255)] >> 32);
        lT[tp]       = (tp == 0 || (unsigned)(qT[SW(tp - 1)] >> 32) != h0) ? tp : 0;
        lT[tp + 256] = (hp != h1) ? (tp + 256) : 0;
    } else {
        const u64 v0 = qS[SW(tp)], v1 = qS[SW(tp + 256)];
        sS[tp]       = __uint_as_float((unsigned)v0);
        sS[tp + 256] = __uint_as_float((unsigned)v1);
        const unsigned h0 = (unsigned)(v0 >> 32), h1 = (unsigned)(v1 >> 32);
        const unsigned hp = (unsigned)(qS[SW(tp + 255)] >> 32);
        lS[tp]       = (tp == 0 || (unsigned)(qS[SW(tp - 1)] >> 32) != h0) ? tp : 0;
        lS[tp + 256] = (hp != h1) ? (tp + 256) : 0;
    }
    __syncthreads();

    // ---- inclusive suffix-sum (E) + inclusive max-scan (lb), wave split ----
    for (int st = 1; st < 512; st <<= 1) {
        float a0, a1; int m0, m1;
        if (t < 256) {
            a0 = (tp + st < 512) ? sT[tp + st] : 0.0f;
            a1 = (tp + 256 + st < 512) ? sT[tp + 256 + st] : 0.0f;
            m0 = (tp >= st) ? lT[tp - st] : 0;
            m1 = lT[tp + 256 - st];         // tp+256 >= st always (st <= 256)
        } else {
            a0 = (tp + st < 512) ? sS[tp + st] : 0.0f;
            a1 = (tp + 256 + st < 512) ? sS[tp + 256 + st] : 0.0f;
            m0 = (tp >= st) ? lS[tp - st] : 0;
            m1 = lS[tp + 256 - st];
        }
        __syncthreads();
        if (t < 256) {
            sT[tp] += a0; sT[tp + 256] += a1;
            lT[tp] = max(lT[tp], m0); lT[tp + 256] = max(lT[tp + 256], m1);
        } else {
            sS[tp] += a0; sS[tp + 256] += a1;
            lS[tp] = max(lS[tp], m0); lS[tp + 256] = max(lS[tp + 256], m1);
        }
        __syncthreads();
    }

    // ---- per-position log terms (both criteria), block reduce ----
    float term = logf(sT[lT[t]]) + logf(sS[lS[t]]);
#pragma unroll
    for (int off = 32; off > 0; off >>= 1) term += __shfl_down(term, off, 64);
    __syncthreads();                        // redA reuse hazard
    if (lane == 0) redA[wid] = term;
    __syncthreads();

    if (t == 0) {
        float tt = 0.0f;
#pragma unroll
        for (int w = 0; w < 8; ++w) tt += redA[w];
        atomicAdd(acc, lsum - 0.5f * tt + diag_part);
        __threadfence();
        const unsigned old = atomicAdd(cnt, 1u);
        if (old == (unsigned)(gridDim.x - 1)) {     // last block finalizes
            const float total = atomicAdd(acc, 0.0f);
            out[0] = -total / NPAIRS;
        }
    }
}

extern "C" void kernel_launch(void* const* d_in, const int* in_sizes, int n_in,
                              void* d_out, int out_size, void* d_ws, size_t ws_size,
                              hipStream_t stream) {
    const float* f      = (const float*)d_in[0];  // (512, 256) fp32
    const float* labels = (const float*)d_in[1];  // (512, 9)   fp32
    float* out = (float*)d_out;                   // scalar fp32
    float* ws  = (float*)d_ws;

    float*    rot  = ws;                   // 512*9
    float*    tvec = rot + N * 9;          // 512*3
    float*    nrm  = tvec + N * 3;         // 512
    float*    acc  = nrm + N;              // 1
    unsigned* cnt  = (unsigned*)(acc + 1); // 1

    prep_kernel<<<N, 64, 0, stream>>>(f, labels, rot, tvec, nrm, acc, cnt);
    fused_row_kernel<<<N, 512, 0, stream>>>(f, rot, tvec, nrm, acc, cnt, out);
}

// Round 7
// 58.875 us; speedup vs baseline: 1.0267x; 1.0267x over previous
//
#include <hip/hip_runtime.h>
#include <math.h>

#define N 512
#define D 256
#define NPAIRS 261632.0f  // 512*511

typedef unsigned long long u64;
typedef unsigned int u32;

__constant__ float kRad2Deg = 57.29577951308232f; // 180/pi

__device__ __forceinline__ u64 shfl_xor_u64(u64 v, int m) {
    u32 lo = (u32)v, hi = (u32)(v >> 32);
    lo = (u32)__shfl_xor((int)lo, m, 64);
    hi = (u32)__shfl_xor((int)hi, m, 64);
    return ((u64)hi << 32) | (u64)lo;
}

// ---------------------------------------------------------------------------
// Kernel 1: per-row prep (as R5/R6, verified). Block = row i, 64 lanes.
// nrm[i] = ||f_i||^2; lane 0 does pose chain; block 0 zeroes acc/cnt.
// ---------------------------------------------------------------------------
__global__ __launch_bounds__(64) void prep_kernel(
        const float* __restrict__ f,
        const float* __restrict__ labels,
        float* __restrict__ rot,
        float* __restrict__ tvec,
        float* __restrict__ nrm,
        float* __restrict__ acc,
        unsigned* __restrict__ cnt) {
    const int i = blockIdx.x;
    const int l = threadIdx.x;

    const float4 v = ((const float4*)(f + i * D))[l];
    float ss = v.x * v.x + v.y * v.y + v.z * v.z + v.w * v.w;
#pragma unroll
    for (int off = 32; off > 0; off >>= 1) ss += __shfl_down(ss, off, 64);

    if (l == 0) {
        nrm[i] = ss;
        const float* p = labels + i * 9;
        float a1x = p[0], a1y = p[1], a1z = p[2];
        float a2x = p[3], a2y = p[4], a2z = p[5];
        float n1 = sqrtf(a1x * a1x + a1y * a1y + a1z * a1z);
        float b1x = a1x / n1, b1y = a1y / n1, b1z = a1z / n1;
        float dp = b1x * a2x + b1y * a2y + b1z * a2z;
        float cx = a2x - dp * b1x, cy = a2y - dp * b1y, cz = a2z - dp * b1z;
        float n2 = sqrtf(cx * cx + cy * cy + cz * cz);
        float b2x = cx / n2, b2y = cy / n2, b2z = cz / n2;
        float b3x = b1y * b2z - b1z * b2y;
        float b3y = b1z * b2x - b1x * b2z;
        float b3z = b1x * b2y - b1y * b2x;
        float det = b1x * (b2y * b3z - b2z * b3y)
                  - b1y * (b2x * b3z - b2z * b3x)
                  + b1z * (b2x * b3y - b2y * b3x);
        float inv = 1.0f / cbrtf(det);
        float* r = rot + i * 9;
        r[0] = b1x * inv; r[1] = b1y * inv; r[2] = b1z * inv;
        r[3] = b2x * inv; r[4] = b2y * inv; r[5] = b2z * inv;
        r[6] = b3x * inv; r[7] = b3y * inv; r[8] = b3z * inv;
        tvec[i * 3 + 0] = p[6];
        tvec[i * 3 + 1] = p[7];
        tvec[i * 3 + 2] = p[8];
        if (i == 0) { acc[0] = 0.0f; cnt[0] = 0u; }
    }
}

// ---------------------------------------------------------------------------
// Kernel 2: Gram matrix G = f * f^T (coalesced, LDS-tiled). 16x16 output
// tile per 256-thread block; K in chunks of 64. Both operands are row-major
// with k contiguous -> all global loads are float4-coalesced.
// ---------------------------------------------------------------------------
__global__ __launch_bounds__(256) void gram_kernel(
        const float* __restrict__ f,
        float* __restrict__ G) {
    __shared__ __attribute__((aligned(16))) float As[16][68]; // 68: pad, 16B-aligned rows
    __shared__ __attribute__((aligned(16))) float Bs[16][68];
    const int tx = threadIdx.x & 15, ty = threadIdx.x >> 4;
    const int bi = (blockIdx.x >> 5) << 4;
    const int bj = (blockIdx.x & 31) << 4;

    float accv = 0.0f;
#pragma unroll
    for (int k0 = 0; k0 < D; k0 += 64) {
        const float4 av = *(const float4*)(f + (bi + ty) * D + k0 + tx * 4);
        const float4 bv = *(const float4*)(f + (bj + ty) * D + k0 + tx * 4);
        __syncthreads();
        *(float4*)&As[ty][tx * 4] = av;
        *(float4*)&Bs[ty][tx * 4] = bv;
        __syncthreads();
#pragma unroll
        for (int kk = 0; kk < 16; ++kk) {
            const float4 a = *(const float4*)&As[ty][kk * 4];
            const float4 b = *(const float4*)&Bs[tx][kk * 4];
            accv += a.x * b.x; accv += a.y * b.y;
            accv += a.z * b.z; accv += a.w * b.w;
        }
    }
    G[(bi + ty) * N + bj + tx] = accv;
}

// ---------------------------------------------------------------------------
// Kernel 3: per-wave row processing — NO LDS arrays, NO barriers.
// Block = 256 threads = 4 waves; wave w handles (row = 2*blockIdx.x + (w>>1),
// criterion = w&1 ? SHIFT : THETA). Element e = r*64 + lane (r = 0..7).
//  1. build (key<<32)|E packed u64 in 8 regs (d2 from Gram row, dot-form)
//  2. in-register bitonic sort (XOR network): jj>=64 -> cross-reg in-thread,
//     jj<64 -> shfl_xor. 45 stages, fully unrolled.
//  3. suffix-sum of E (lane shuffle scan + cross-reg carry)
//  4. tie-run-head value propagation ("last valid" select scan)
//  5. sum of log terms; wave contribution -> one atomicAdd; last of the
//     1024 waves finalizes out[0].
// Diagonal handling: thresholds computed directly (theta_ii from rotI with
// identical op order -> bit-exact; shift_ii = 0); E_ii = 0, L_ii = 0.
// ---------------------------------------------------------------------------
__global__ __launch_bounds__(256) void row_kernel(
        const float* __restrict__ G,
        const float* __restrict__ rot,
        const float* __restrict__ tvec,
        const float* __restrict__ nrm,
        float* __restrict__ acc,
        unsigned* __restrict__ cnt,
        float* __restrict__ out) {
    const int tid  = threadIdx.x;
    const int lane = tid & 63;
    const int wid  = tid >> 6;                  // 0..3
    const int i    = blockIdx.x * 2 + (wid >> 1);
    const bool isT = (wid & 1) == 0;

    float rotI[9];
#pragma unroll
    for (int c = 0; c < 9; ++c) rotI[c] = rot[i * 9 + c];
    const float tIx = tvec[i * 3 + 0];
    const float tIy = tvec[i * 3 + 1];
    const float tIz = tvec[i * 3 + 2];
    const float ni  = nrm[i];

    // diagonal threshold (bit-exact vs the in-wave j==i element: same op order)
    float dthr;
    if (isT) {
        float trii = 0.0f;
#pragma unroll
        for (int c = 0; c < 9; ++c) trii += rotI[c] * rotI[c];
        float ctv = fminf(1.0f, fmaxf(-1.0f, (trii - 1.0f) * 0.5f));
        dthr = acosf(ctv) * kRad2Deg;
    } else {
        dthr = 0.0f;
    }

    // ---- build packed elements + lsum + direct diag denominator ----
    u64 q[8];
    float lsum = 0.0f, dden = 0.0f;
#pragma unroll
    for (int r = 0; r < 8; ++r) {
        const int e = r * 64 + lane;            // column j
        const float gij = G[i * N + e];         // coalesced
        const float d2  = ni + nrm[e] - 2.0f * gij;
        float L, Ev;
        if (e == i) { L = 0.0f; Ev = 0.0f; }    // exact reference diagonal
        else {
            const float dist = (d2 > 0.0f) ? sqrtf(d2) : 0.0f;
            L  = -0.5f * dist;                  // TEMPERATURE=2; rowmax==0 (no-op)
            Ev = expf(L);
        }
        float keyv;
        if (isT) {
            float tr8 = 0.0f;
#pragma unroll
            for (int c = 0; c < 9; ++c) tr8 += rotI[c] * rot[e * 9 + c];
            float ctv = fminf(1.0f, fmaxf(-1.0f, (tr8 - 1.0f) * 0.5f));
            keyv = acosf(ctv) * kRad2Deg;
        } else {
            const float dx = tIx - tvec[e * 3 + 0];
            const float dy = tIy - tvec[e * 3 + 1];
            const float dz = tIz - tvec[e * 3 + 2];
            const float sd2 = dx * dx + dy * dy + dz * dz;
            keyv = ((sd2 > 0.0f) ? sqrtf(sd2) : 0.0f) * 100.0f;
        }
        q[r]  = ((u64)__float_as_uint(keyv) << 32) | (u64)__float_as_uint(Ev);
        lsum += L;
        dden += (keyv >= dthr) ? Ev : 0.0f;
    }
#pragma unroll
    for (int off = 32; off > 0; off >>= 1) {
        lsum += __shfl_down(lsum, off, 64);
        dden += __shfl_down(dden, off, 64);
    }

    // ---- in-register bitonic sort, ascending by (key, E) ----
#pragma unroll
    for (int kb = 1; kb <= 9; ++kb) {
        const unsigned k = 1u << kb;
#pragma unroll
        for (int jb = kb - 1; jb >= 0; --jb) {
            if (jb >= 6) {
                const int rx = 1 << (jb - 6);
#pragma unroll
                for (int r = 0; r < 8; ++r) {
                    if ((r & rx) == 0) {
                        const int rp = r | rx;
                        const bool up = ((((unsigned)r << 6) & k) == 0); // k>=128 here
                        const u64 a = q[r], b = q[rp];
                        const bool altb = a < b;
                        const u64 mn = altb ? a : b;
                        const u64 mx = altb ? b : a;
                        q[r]  = up ? mn : mx;
                        q[rp] = up ? mx : mn;
                    }
                }
            } else {
                const int jj = 1 << jb;
#pragma unroll
                for (int r = 0; r < 8; ++r) {
                    const u64 p = shfl_xor_u64(q[r], jj);
                    bool up;
                    if (kb >= 6) up = ((((unsigned)r << 6) & k) == 0); // compile-time
                    else         up = ((lane & k) == 0);
                    const bool lower   = ((lane & jj) == 0);
                    const bool keepmin = (up == lower);
                    const u64 a = q[r];
                    const bool altb = a < p;
                    q[r] = (altb == keepmin) ? a : p;
                }
            }
        }
    }

    // ---- unpack ----
    u32 key[8]; float sfx[8];
#pragma unroll
    for (int r = 0; r < 8; ++r) {
        key[r] = (u32)(q[r] >> 32);
        sfx[r] = __uint_as_float((u32)q[r]);
    }

    // ---- inclusive suffix-sum over e = r*64+lane ----
#pragma unroll
    for (int off = 1; off < 64; off <<= 1) {
#pragma unroll
        for (int r = 0; r < 8; ++r) {
            const float t = __shfl_down(sfx[r], off, 64);
            if (lane + off < 64) sfx[r] += t;
        }
    }
    {
        float carry = 0.0f;
#pragma unroll
        for (int r = 7; r >= 0; --r) {
            const float tot = __shfl(sfx[r], 0, 64);  // reg total (before carry)
            sfx[r] += carry;
            carry  += tot;
        }
    }

    // ---- tie-run-head propagation: hv[e] = sfx at run start (>= semantics) ----
    float hv[8];
#pragma unroll
    for (int r = 0; r < 8; ++r) {
        u32 kprev = (u32)__shfl_up((int)key[r], 1, 64);
        if (r > 0) {
            const u32 c = (u32)__shfl((int)key[r - 1], 63, 64);
            kprev = (lane == 0) ? c : kprev;
        }
        const bool head = (r == 0 && lane == 0) ? true : (key[r] != kprev);
        hv[r] = head ? sfx[r] : -1.0f;
    }
#pragma unroll
    for (int off = 1; off < 64; off <<= 1) {
#pragma unroll
        for (int r = 0; r < 8; ++r) {
            const float t = __shfl_up(hv[r], off, 64);
            if (lane >= off && hv[r] < 0.0f) hv[r] = t;
        }
    }
    {
        float carry2 = 0.0f;                    // e=0 is a head -> reg0 fully valid
#pragma unroll
        for (int r = 0; r < 8; ++r) {
            if (hv[r] < 0.0f) hv[r] = carry2;
            carry2 = __shfl(hv[r], 63, 64);
        }
    }

    // ---- sum of per-position log terms ----
    float tsum = 0.0f;
#pragma unroll
    for (int r = 0; r < 8; ++r) tsum += logf(hv[r]);
#pragma unroll
    for (int off = 32; off > 0; off >>= 1) tsum += __shfl_down(tsum, off, 64);

    // ---- contribution + last-wave finalize ----
    if (lane == 0) {
        // Sum(terms) over all 512 positions includes the diagonal's term
        // (== log dden); +0.5*log(dden) cancels it (verified R4-R6).
        float contrib = -0.5f * tsum + 0.5f * logf(dden);
        if (isT) contrib += lsum;
        atomicAdd(acc, contrib);
        __threadfence();
        const unsigned old = atomicAdd(cnt, 1u);
        if (old == (unsigned)(gridDim.x * 4 - 1)) {     // 1024 waves
            const float total = atomicAdd(acc, 0.0f);
            out[0] = -total / NPAIRS;
        }
    }
}

extern "C" void kernel_launch(void* const* d_in, const int* in_sizes, int n_in,
                              void* d_out, int out_size, void* d_ws, size_t ws_size,
                              hipStream_t stream) {
    const float* f      = (const float*)d_in[0];  // (512, 256) fp32
    const float* labels = (const float*)d_in[1];  // (512, 9)   fp32
    float* out = (float*)d_out;                   // scalar fp32
    float* ws  = (float*)d_ws;

    float*    rot  = ws;                    // 512*9
    float*    tvec = rot + N * 9;           // 512*3
    float*    nrm  = tvec + N * 3;          // 512
    float*    acc  = nrm + N;               // 1
    unsigned* cnt  = (unsigned*)(acc + 1);  // 1
    float*    G    = acc + 16;              // 512*512 (1 MB)

    prep_kernel<<<N, 64, 0, stream>>>(f, labels, rot, tvec, nrm, acc, cnt);
    gram_kernel<<<(N / 16) * (N / 16), 256, 0, stream>>>(f, G);
    row_kernel<<<N / 2, 256, 0, stream>>>(G, rot, tvec, nrm, acc, cnt, out);
}